// Round 3
// baseline (101.445 us; speedup 1.0000x reference)
//
#include <hip/hip_runtime.h>
#include <math.h>

#define T_LEN 2048
#define KNUM 10000
#define MAXKL 11
#define BPK 8                  // rocket kernels per block
#define NBLK (KNUM / BPK)      // 1250 blocks
#define XOFF 3                 // XP[3] = ref xp[0] (left zero pad); XP[4..2051] = x
#define XP_SZ 2064             // max read idx 2053 (V=2 overread, discarded), zeroed to 2055
#define NB2 40                 // classifier partial blocks
#define CHUNK2 500             // features per classifier block
#define NCLS 10

// ---------------- feats: per-L position loop, 2 positions/thread ----------------
// Adjacent reads XP[o], XP[o+1] merge into one ds_read2_b32 (4B-aligned safe).
template<int L>
__device__ __forceinline__ void conv_loop(const float* __restrict__ XP, int tid,
    int out_len, int s0, int d, const float* __restrict__ wr, float bias,
    int& cnt, float& mx)
{
    for (int s2 = tid * 2; s2 < out_len; s2 += 512) {
        const int base = XOFF + s0 + s2;
        float a0 = bias, a1 = bias;
#pragma unroll
        for (int j = 0; j < L; ++j) {
            const float* p = XP + base + j * d;
            const float p0 = p[0];
            const float p1 = p[1];
            a0 = fmaf(wr[j], p0, a0);
            a1 = fmaf(wr[j], p1, a1);
        }
        cnt += (a0 > 0.0f) ? 1 : 0;
        mx = fmaxf(mx, a0);
        if (s2 + 1 < out_len) {
            cnt += (a1 > 0.0f) ? 1 : 0;
            mx = fmaxf(mx, a1);
        }
    }
}

__global__ __launch_bounds__(256) void rocket_feats_kernel(
    const float* __restrict__ x, const float* __restrict__ w,
    const float* __restrict__ b, const int* __restrict__ dil,
    const int* __restrict__ pad, const int* __restrict__ Ls,
    float* __restrict__ feats)
{
    __shared__ float XP[XP_SZ];
    __shared__ float rmx[BPK][4];
    __shared__ int   rcnt[BPK][4];

    const int tid = threadIdx.x;

    // stage signal once per block: XP[3]=0, XP[4..2051]=x, XP[2052..2055]=0
    {
        const float4* x4 = (const float4*)x;
        float4* XP4 = (float4*)XP;
#pragma unroll
        for (int it = 0; it < T_LEN / 4 / 256; ++it)
            XP4[1 + it * 256 + tid] = x4[it * 256 + tid];
        if (tid < 4) XP[tid] = 0.0f;             // 0..3 (incl. left pad at 3)
        else if (tid < 8) XP[2048 + tid] = 0.0f; // 2052..2055 (right pad + overread)
    }
    __syncthreads();

    const int k0 = blockIdx.x * BPK;
    for (int kk = 0; kk < BPK; ++kk) {
        const int k = k0 + kk;
        float wr[MAXKL];
#pragma unroll
        for (int j = 0; j < MAXKL; ++j) wr[j] = w[k * MAXKL + j];
        const float bias = b[k];
        const int d = dil[k];
        const int p = pad[k];
        const int L = Ls[k];
        const int out_len = T_LEN + 2 * p - d * (L - 1);
        const int s0 = 1 - p;

        int cnt = 0;
        float mx = -INFINITY;
        if (L == 7)       conv_loop<7>(XP, tid, out_len, s0, d, wr, bias, cnt, mx);
        else if (L == 9)  conv_loop<9>(XP, tid, out_len, s0, d, wr, bias, cnt, mx);
        else              conv_loop<11>(XP, tid, out_len, s0, d, wr, bias, cnt, mx);

        // wave reduce (64 lanes)
#pragma unroll
        for (int off = 32; off > 0; off >>= 1) {
            cnt += __shfl_down(cnt, off);
            mx = fmaxf(mx, __shfl_down(mx, off));
        }
        const int wv = tid >> 6;
        if ((tid & 63) == 0) { rmx[kk][wv] = mx; rcnt[kk][wv] = cnt; }
        __syncthreads();
        if (tid == 0) {
            const float m = fmaxf(fmaxf(rmx[kk][0], rmx[kk][1]),
                                  fmaxf(rmx[kk][2], rmx[kk][3]));
            const int c = rcnt[kk][0] + rcnt[kk][1] + rcnt[kk][2] + rcnt[kk][3];
            feats[k]        = (float)c / (float)out_len;   // ppv
            feats[KNUM + k] = m;                           // max
        }
        // no second barrier: next kk writes different rmx/rcnt slots
    }
}

// ---------------- Kernel 2: partial GEMV feats @ Wc ----------------
__global__ __launch_bounds__(256) void rocket_logits_kernel(
    const float* __restrict__ feats, const float* __restrict__ Wc,
    float* __restrict__ partials)   // [NB2 * NCLS]
{
    float acc[NCLS];
#pragma unroll
    for (int c = 0; c < NCLS; ++c) acc[c] = 0.0f;

    const int fbeg = blockIdx.x * CHUNK2;
    const int fend = fbeg + CHUNK2;
    for (int f = fbeg + threadIdx.x; f < fend; f += 256) {
        const float v = feats[f];
        const float* __restrict__ wrow = Wc + (size_t)f * NCLS;
#pragma unroll
        for (int c = 0; c < NCLS; ++c)
            acc[c] = fmaf(v, wrow[c], acc[c]);
    }

#pragma unroll
    for (int c = 0; c < NCLS; ++c) {
#pragma unroll
        for (int off = 32; off > 0; off >>= 1)
            acc[c] += __shfl_down(acc[c], off);
    }
    __shared__ float lds[4][NCLS];
    const int wave = threadIdx.x >> 6;
    if ((threadIdx.x & 63) == 0) {
#pragma unroll
        for (int c = 0; c < NCLS; ++c) lds[wave][c] = acc[c];
    }
    __syncthreads();
    if (threadIdx.x == 0) {
#pragma unroll
        for (int c = 0; c < NCLS; ++c)
            partials[blockIdx.x * NCLS + c] =
                lds[0][c] + lds[1][c] + lds[2][c] + lds[3][c];
    }
}

// ---------------- Kernel 3: final reduce + bias + softmax ----------------
__global__ __launch_bounds__(64) void rocket_softmax_kernel(
    const float* __restrict__ partials, const float* __restrict__ bc,
    float* __restrict__ out)
{
    __shared__ float lg[NCLS];
    const int t = threadIdx.x;
    if (t < NCLS) {
        float s = bc[t];
        for (int i = 0; i < NB2; ++i) s += partials[i * NCLS + t];
        lg[t] = s;
    }
    __syncthreads();
    if (t == 0) {
        float m = lg[0];
#pragma unroll
        for (int i = 1; i < NCLS; ++i) m = fmaxf(m, lg[i]);
        float e[NCLS];
        float se = 0.0f;
#pragma unroll
        for (int i = 0; i < NCLS; ++i) { e[i] = expf(lg[i] - m); se += e[i]; }
        const float inv = 1.0f / se;
#pragma unroll
        for (int i = 0; i < NCLS; ++i) out[i] = e[i] * inv;
    }
}

extern "C" void kernel_launch(void* const* d_in, const int* in_sizes, int n_in,
                              void* d_out, int out_size, void* d_ws, size_t ws_size,
                              hipStream_t stream) {
    const float* x   = (const float*)d_in[0];
    const float* w   = (const float*)d_in[1];
    const float* b   = (const float*)d_in[2];
    const int*   dil = (const int*)d_in[3];
    const int*   pad = (const int*)d_in[4];
    const int*   Ls  = (const int*)d_in[5];
    const float* Wc  = (const float*)d_in[6];
    const float* bc  = (const float*)d_in[7];
    float* out = (float*)d_out;

    float* feats    = (float*)d_ws;                       // 2*KNUM floats
    float* partials = feats + 2 * KNUM;                   // NB2*NCLS floats

    rocket_feats_kernel<<<NBLK, 256, 0, stream>>>(x, w, b, dil, pad, Ls, feats);
    rocket_logits_kernel<<<NB2, 256, 0, stream>>>(feats, Wc, partials);
    rocket_softmax_kernel<<<1, 64, 0, stream>>>(partials, bc, out);
}

// Round 4
// 100.656 us; speedup vs baseline: 1.0078x; 1.0078x over previous
//
#include <hip/hip_runtime.h>
#include <math.h>

#define T_LEN 2048
#define KNUM 10000
#define MAXKL 11
#define BPK 8                  // rocket kernels per block
#define NBLK (KNUM / BPK)      // 1250 blocks
#define XOFF 3                 // XP[3] = ref xp[0] (left zero pad); XP[4..2051] = x
#define XP_SZ 2064             // max read idx 2053 (V=2 overread, discarded), zeroed to 2055
#define NCLS 10
#define RGRP 50                // partial-rows summed per reducer thread-group
#define NGRP (NBLK / RGRP)     // 25 groups

// ---------------- feats: per-L position loop, 2 positions/thread ----------------
// Adjacent reads XP[o], XP[o+1] merge into one ds_read2_b32 (4B-aligned safe).
template<int L>
__device__ __forceinline__ void conv_loop(const float* __restrict__ XP, int tid,
    int out_len, int s0, int d, const float* __restrict__ wr, float bias,
    int& cnt, float& mx)
{
    for (int s2 = tid * 2; s2 < out_len; s2 += 512) {
        const int base = XOFF + s0 + s2;
        float a0 = bias, a1 = bias;
#pragma unroll
        for (int j = 0; j < L; ++j) {
            const float* p = XP + base + j * d;
            const float p0 = p[0];
            const float p1 = p[1];
            a0 = fmaf(wr[j], p0, a0);
            a1 = fmaf(wr[j], p1, a1);
        }
        cnt += (a0 > 0.0f) ? 1 : 0;
        mx = fmaxf(mx, a0);
        if (s2 + 1 < out_len) {
            cnt += (a1 > 0.0f) ? 1 : 0;
            mx = fmaxf(mx, a1);
        }
    }
}

// ---------- Kernel A: features + per-block classifier partials ----------
__global__ __launch_bounds__(256) void rocket_feats_kernel(
    const float* __restrict__ x, const float* __restrict__ w,
    const float* __restrict__ b, const int* __restrict__ dil,
    const int* __restrict__ pad, const int* __restrict__ Ls,
    const float* __restrict__ Wc,
    float* __restrict__ partials)      // [NBLK][NCLS]
{
    __shared__ float XP[XP_SZ];
    __shared__ float rmx[BPK][4];
    __shared__ int   rcnt[BPK][4];
    __shared__ float pv[BPK];          // ppv per kernel in this block
    __shared__ float mv[BPK];          // max per kernel in this block

    const int tid = threadIdx.x;

    // stage signal once per block: XP[3]=0, XP[4..2051]=x, XP[2052..2055]=0
    {
        const float4* x4 = (const float4*)x;
        float4* XP4 = (float4*)XP;
#pragma unroll
        for (int it = 0; it < T_LEN / 4 / 256; ++it)
            XP4[1 + it * 256 + tid] = x4[it * 256 + tid];
        if (tid < 4) XP[tid] = 0.0f;             // 0..3 (incl. left pad at 3)
        else if (tid < 8) XP[2048 + tid] = 0.0f; // 2052..2055 (right pad + overread)
    }
    __syncthreads();

    const int k0 = blockIdx.x * BPK;
    for (int kk = 0; kk < BPK; ++kk) {
        const int k = k0 + kk;
        float wr[MAXKL];
#pragma unroll
        for (int j = 0; j < MAXKL; ++j) wr[j] = w[k * MAXKL + j];
        const float bias = b[k];
        const int d = dil[k];
        const int p = pad[k];
        const int L = Ls[k];
        const int out_len = T_LEN + 2 * p - d * (L - 1);
        const int s0 = 1 - p;

        int cnt = 0;
        float mx = -INFINITY;
        if (L == 7)       conv_loop<7>(XP, tid, out_len, s0, d, wr, bias, cnt, mx);
        else if (L == 9)  conv_loop<9>(XP, tid, out_len, s0, d, wr, bias, cnt, mx);
        else              conv_loop<11>(XP, tid, out_len, s0, d, wr, bias, cnt, mx);

        // wave reduce (64 lanes)
#pragma unroll
        for (int off = 32; off > 0; off >>= 1) {
            cnt += __shfl_down(cnt, off);
            mx = fmaxf(mx, __shfl_down(mx, off));
        }
        const int wv = tid >> 6;
        if ((tid & 63) == 0) { rmx[kk][wv] = mx; rcnt[kk][wv] = cnt; }
        __syncthreads();
        if (tid == 0) {
            const float m = fmaxf(fmaxf(rmx[kk][0], rmx[kk][1]),
                                  fmaxf(rmx[kk][2], rmx[kk][3]));
            const int c = rcnt[kk][0] + rcnt[kk][1] + rcnt[kk][2] + rcnt[kk][3];
            pv[kk] = (float)c / (float)out_len;   // ppv
            mv[kk] = m;                           // max
        }
        // no extra barrier needed: next kk uses different rmx/rcnt slots
    }
    __syncthreads();

    // classifier partial: partials[blk][c] = sum_kk pv*Wc[k][c] + mv*Wc[K+k][c]
    if (tid < NCLS) {
        float acc = 0.0f;
#pragma unroll
        for (int kk = 0; kk < BPK; ++kk) {
            const int k = k0 + kk;
            acc = fmaf(pv[kk], Wc[(size_t)k * NCLS + tid], acc);
            acc = fmaf(mv[kk], Wc[(size_t)(KNUM + k) * NCLS + tid], acc);
        }
        partials[blockIdx.x * NCLS + tid] = acc;
    }
}

// ---------- Kernel B: reduce partials + bias + softmax ----------
__global__ __launch_bounds__(256) void rocket_softmax_kernel(
    const float* __restrict__ partials, const float* __restrict__ bc,
    float* __restrict__ out)
{
    __shared__ float lds[NGRP][NCLS];
    __shared__ float lg[NCLS];
    const int t = threadIdx.x;

    if (t < NGRP * NCLS) {
        const int c = t % NCLS;
        const int g = t / NCLS;
        float s = 0.0f;
        const float* p = partials + (size_t)g * RGRP * NCLS + c;
        for (int i = 0; i < RGRP; ++i) s += p[i * NCLS];
        lds[g][c] = s;
    }
    __syncthreads();
    if (t < NCLS) {
        float s = bc[t];
#pragma unroll
        for (int g = 0; g < NGRP; ++g) s += lds[g][t];
        lg[t] = s;
    }
    __syncthreads();
    if (t == 0) {
        float m = lg[0];
#pragma unroll
        for (int i = 1; i < NCLS; ++i) m = fmaxf(m, lg[i]);
        float e[NCLS];
        float se = 0.0f;
#pragma unroll
        for (int i = 0; i < NCLS; ++i) { e[i] = expf(lg[i] - m); se += e[i]; }
        const float inv = 1.0f / se;
#pragma unroll
        for (int i = 0; i < NCLS; ++i) out[i] = e[i] * inv;
    }
}

extern "C" void kernel_launch(void* const* d_in, const int* in_sizes, int n_in,
                              void* d_out, int out_size, void* d_ws, size_t ws_size,
                              hipStream_t stream) {
    const float* x   = (const float*)d_in[0];
    const float* w   = (const float*)d_in[1];
    const float* b   = (const float*)d_in[2];
    const int*   dil = (const int*)d_in[3];
    const int*   pad = (const int*)d_in[4];
    const int*   Ls  = (const int*)d_in[5];
    const float* Wc  = (const float*)d_in[6];
    const float* bc  = (const float*)d_in[7];
    float* out = (float*)d_out;

    float* partials = (float*)d_ws;    // NBLK*NCLS floats

    rocket_feats_kernel<<<NBLK, 256, 0, stream>>>(x, w, b, dil, pad, Ls, Wc, partials);
    rocket_softmax_kernel<<<1, 256, 0, stream>>>(partials, bc, out);
}